// Round 2
// baseline (1030.537 us; speedup 1.0000x reference)
//
#include <hip/hip_runtime.h>

// SNN block: cur = x @ W^T + b  (f32 GEMM), then sequential leaky-integrate-fire scan.
// T=200, B=256, D_IN=512, D_H=512. BETA=0.9, THRESHOLD=1.0.
// d_out = [spk_rec (T*B*H) | mem_rec (T*B*H)] f32.
// GEMM writes cur into the mem_rec half of d_out; scan runs in-place.
//
// Numerics contract: per-output ascending-k "acc += a*b" chain, then "+ bias"
// once at the end — matched the np reference bit-exactly (absmax 0.0). Do not
// reassociate.

#define T_STEPS 200
#define BATCH   256
#define D_INN   512
#define D_HH    512

constexpr int MM = T_STEPS * BATCH;  // 51200
constexpr int NN = D_HH;             // 512
constexpr int KK = D_INN;            // 512

#define BM 256
#define BN 128
#define BK 16

// ---------------- GEMM: C[m][n] = sum_k A[m][k]*W[n][k] + bias[n] ----------------
// 256 threads, 16x8 micro-tile per thread (BM=256 x BN=128), BK=16.
// LDS bytes/FMA = 0.75 -> VALU-issue-bound, all LDS accesses <=2-way (free).
__global__ __launch_bounds__(256, 2) void gemm_nt_f32(const float* __restrict__ A,
                                                      const float* __restrict__ W,
                                                      const float* __restrict__ bias,
                                                      float* __restrict__ C) {
    __shared__ float As[BK][260];  // [k][m], pad 260: 260%32=4 -> staging writes 2-way
    __shared__ float Bs[BK][132];  // [k][n], pad 132

    const int tid = threadIdx.x;
    const int tx = tid & 15;        // 0..15 -> col group (cols tx*4 and 64+tx*4)
    const int ty = tid >> 4;        // 0..15 -> row group (rows ty*16..ty*16+15)
    const int row0 = blockIdx.x * BM;
    const int col0 = blockIdx.y * BN;

    // staging: 4 threads per row cover 16 k's; 64 rows per pass
    const int lr = tid >> 2;          // 0..63
    const int lk = (tid & 3) * 4;     // 0,4,8,12

    float acc[16][8] = {};
    float4 ra[4], rb[2];

    auto loadreg = [&](int k0) {
#pragma unroll
        for (int p = 0; p < 4; ++p)
            ra[p] = *reinterpret_cast<const float4*>(&A[(size_t)(row0 + lr + p * 64) * KK + k0 + lk]);
#pragma unroll
        for (int p = 0; p < 2; ++p)
            rb[p] = *reinterpret_cast<const float4*>(&W[(size_t)(col0 + lr + p * 64) * KK + k0 + lk]);
    };

    loadreg(0);

    for (int kt = 0; kt < KK / BK; ++kt) {
        // regs -> LDS (transposed)
#pragma unroll
        for (int p = 0; p < 4; ++p) {
            const int r = lr + p * 64;
            As[lk + 0][r] = ra[p].x; As[lk + 1][r] = ra[p].y;
            As[lk + 2][r] = ra[p].z; As[lk + 3][r] = ra[p].w;
        }
#pragma unroll
        for (int p = 0; p < 2; ++p) {
            const int r = lr + p * 64;
            Bs[lk + 0][r] = rb[p].x; Bs[lk + 1][r] = rb[p].y;
            Bs[lk + 2][r] = rb[p].z; Bs[lk + 3][r] = rb[p].w;
        }
        __syncthreads();

        // prefetch next tile's globals under the compute phase
        if (kt + 1 < KK / BK) loadreg((kt + 1) * BK);

#pragma unroll
        for (int k = 0; k < BK; ++k) {
            float a[16], b[8];
            const float4 t0 = *reinterpret_cast<const float4*>(&As[k][ty * 16 + 0]);
            const float4 t1 = *reinterpret_cast<const float4*>(&As[k][ty * 16 + 4]);
            const float4 t2 = *reinterpret_cast<const float4*>(&As[k][ty * 16 + 8]);
            const float4 t3 = *reinterpret_cast<const float4*>(&As[k][ty * 16 + 12]);
            a[0]=t0.x; a[1]=t0.y; a[2]=t0.z; a[3]=t0.w;
            a[4]=t1.x; a[5]=t1.y; a[6]=t1.z; a[7]=t1.w;
            a[8]=t2.x; a[9]=t2.y; a[10]=t2.z; a[11]=t2.w;
            a[12]=t3.x; a[13]=t3.y; a[14]=t3.z; a[15]=t3.w;
            const float4 u0 = *reinterpret_cast<const float4*>(&Bs[k][tx * 4]);
            const float4 u1 = *reinterpret_cast<const float4*>(&Bs[k][64 + tx * 4]);
            b[0]=u0.x; b[1]=u0.y; b[2]=u0.z; b[3]=u0.w;
            b[4]=u1.x; b[5]=u1.y; b[6]=u1.z; b[7]=u1.w;
#pragma unroll
            for (int i = 0; i < 16; ++i)
#pragma unroll
                for (int j = 0; j < 8; ++j)
                    acc[i][j] += a[i] * b[j];
        }
        __syncthreads();
    }

    // epilogue: + bias, two float4 stores per row
#pragma unroll
    for (int i = 0; i < 16; ++i) {
        const int r = row0 + ty * 16 + i;
        const int c0 = col0 + tx * 4;
        const int c1 = col0 + 64 + tx * 4;
        float4 o0, o1;
        o0.x = acc[i][0] + bias[c0 + 0];
        o0.y = acc[i][1] + bias[c0 + 1];
        o0.z = acc[i][2] + bias[c0 + 2];
        o0.w = acc[i][3] + bias[c0 + 3];
        o1.x = acc[i][4] + bias[c1 + 0];
        o1.y = acc[i][5] + bias[c1 + 1];
        o1.z = acc[i][6] + bias[c1 + 2];
        o1.w = acc[i][7] + bias[c1 + 3];
        *reinterpret_cast<float4*>(&C[(size_t)r * NN + c0]) = o0;
        *reinterpret_cast<float4*>(&C[(size_t)r * NN + c1]) = o1;
    }
}

// ---------------- Sequential LIF scan (in-place over cur/mem buffer) ----------------
__global__ __launch_bounds__(256) void snn_scan(float* buf, float* spk) {
    const int BH = BATCH * D_HH;  // 131072
    const int i = blockIdx.x * 256 + threadIdx.x;
    float mem = 0.0f;
    float c = buf[i];  // prefetch t=0
    for (int t = 0; t < T_STEPS; ++t) {
        float cn = (t + 1 < T_STEPS) ? buf[(size_t)(t + 1) * BH + i] : 0.0f;
        const float reset = (mem > 1.0f) ? 1.0f : 0.0f;
        mem = 0.9f * mem + c - reset;
        const float s = (mem > 1.0f) ? 1.0f : 0.0f;
        spk[(size_t)t * BH + i] = s;
        buf[(size_t)t * BH + i] = mem;
        c = cn;
    }
}

extern "C" void kernel_launch(void* const* d_in, const int* in_sizes, int n_in,
                              void* d_out, int out_size, void* d_ws, size_t ws_size,
                              hipStream_t stream) {
    const float* x    = (const float*)d_in[0];  // [T,B,D_IN]
    const float* W    = (const float*)d_in[1];  // [D_H,D_IN]
    const float* bias = (const float*)d_in[2];  // [D_H]
    float* out = (float*)d_out;

    const size_t TBH = (size_t)T_STEPS * BATCH * D_HH;
    float* spk = out;        // first half
    float* mem = out + TBH;  // second half; holds cur between the two kernels

    dim3 grid(MM / BM, NN / BN);  // 200 x 4
    gemm_nt_f32<<<grid, 256, 0, stream>>>(x, W, bias, mem);

    snn_scan<<<(BATCH * D_HH) / 256, 256, 0, stream>>>(mem, spk);
}

// Round 3
// 386.025 us; speedup vs baseline: 2.6696x; 2.6696x over previous
//
#include <hip/hip_runtime.h>

// SNN block: cur = x @ W^T + b  (f32 GEMM), then sequential leaky-integrate-fire scan.
// T=200, B=256, D_IN=512, D_H=512. BETA=0.9, THRESHOLD=1.0.
// d_out = [spk_rec (T*B*H) | mem_rec (T*B*H)] f32.
// GEMM writes cur into the mem_rec half of d_out; scan runs in-place.
//
// Numerics contract (verified absmax 0.0 in R1/R2): per-output ascending-k
// "acc += a*b" FMA chain, "+ bias" once at the end. Do not reassociate.
//
// R2 post-mortem: 16x8 micro-tile spilled (VGPR capped 128, 2 GB scratch
// writes). Stay at 8x8 (64 acc). R1 fixes applied here: 2-way B-column split
// (kills the 4-way LDS conflict) + register prefetch of next k-tile + BK=32.

#define T_STEPS 200
#define BATCH   256
#define D_INN   512
#define D_HH    512

constexpr int MM = T_STEPS * BATCH;  // 51200
constexpr int NN = D_HH;             // 512
constexpr int KK = D_INN;            // 512

#define BM 128
#define BN 128
#define BK 32
#define LPAD 132   // 132 % 32 == 4 -> staging writes 2-way, b128-aligned reads

// ---------------- GEMM: C[m][n] = sum_k A[m][k]*W[n][k] + bias[n] ----------------
// 256 threads, 8x8 micro-tile (rows ty*8.., cols tx*4.. and 64+tx*4..).
__global__ __launch_bounds__(256, 3) void gemm_nt_f32(const float* __restrict__ A,
                                                      const float* __restrict__ W,
                                                      const float* __restrict__ bias,
                                                      float* __restrict__ C) {
    __shared__ float As[BK][LPAD];  // [k][m]
    __shared__ float Bs[BK][LPAD];  // [k][n]

    const int tid = threadIdx.x;
    const int tx = tid & 15;        // col group
    const int ty = tid >> 4;        // row group
    const int row0 = blockIdx.x * BM;
    const int col0 = blockIdx.y * BN;

    // staging: 4 threads per row cover 16 k's; 64 rows per pass; 2 k-halves
    const int lr = tid >> 2;          // 0..63
    const int lk = (tid & 3) * 4;     // 0,4,8,12

    const float* Abase = A + (size_t)(row0 + lr) * KK + lk;
    const float* Bbase = W + (size_t)(col0 + lr) * KK + lk;

    float acc[8][8] = {};

    // prefetch registers (named, static — no dynamic indexing)
    float4 ra00, ra01, ra10, ra11;  // ra[p][h]: row half p, k half h
    float4 rb00, rb01, rb10, rb11;

#define LOADREG(k0)                                                        \
    do {                                                                   \
        ra00 = *reinterpret_cast<const float4*>(Abase + (k0));             \
        ra01 = *reinterpret_cast<const float4*>(Abase + (k0) + 16);        \
        ra10 = *reinterpret_cast<const float4*>(Abase + 64 * KK + (k0));   \
        ra11 = *reinterpret_cast<const float4*>(Abase + 64 * KK + (k0) + 16); \
        rb00 = *reinterpret_cast<const float4*>(Bbase + (k0));             \
        rb01 = *reinterpret_cast<const float4*>(Bbase + (k0) + 16);        \
        rb10 = *reinterpret_cast<const float4*>(Bbase + 64 * KK + (k0));   \
        rb11 = *reinterpret_cast<const float4*>(Bbase + 64 * KK + (k0) + 16); \
    } while (0)

#define STOREV(arr, kbase, r, v)                                           \
    do {                                                                   \
        arr[(kbase) + 0][r] = (v).x; arr[(kbase) + 1][r] = (v).y;          \
        arr[(kbase) + 2][r] = (v).z; arr[(kbase) + 3][r] = (v).w;          \
    } while (0)

    LOADREG(0);

    for (int kt = 0; kt < KK / BK; ++kt) {
        __syncthreads();  // previous tile's reads complete before overwrite
        STOREV(As, lk, lr, ra00);
        STOREV(As, 16 + lk, lr, ra01);
        STOREV(As, lk, lr + 64, ra10);
        STOREV(As, 16 + lk, lr + 64, ra11);
        STOREV(Bs, lk, lr, rb00);
        STOREV(Bs, 16 + lk, lr, rb01);
        STOREV(Bs, lk, lr + 64, rb10);
        STOREV(Bs, 16 + lk, lr + 64, rb11);
        __syncthreads();

        if (kt + 1 < KK / BK) LOADREG((kt + 1) * BK);  // hide HBM under compute

#pragma unroll 8
        for (int k = 0; k < BK; ++k) {
            float a[8], b[8];
            const float4 t0 = *reinterpret_cast<const float4*>(&As[k][ty * 8 + 0]);
            const float4 t1 = *reinterpret_cast<const float4*>(&As[k][ty * 8 + 4]);
            a[0]=t0.x; a[1]=t0.y; a[2]=t0.z; a[3]=t0.w;
            a[4]=t1.x; a[5]=t1.y; a[6]=t1.z; a[7]=t1.w;
            const float4 u0 = *reinterpret_cast<const float4*>(&Bs[k][tx * 4]);
            const float4 u1 = *reinterpret_cast<const float4*>(&Bs[k][64 + tx * 4]);
            b[0]=u0.x; b[1]=u0.y; b[2]=u0.z; b[3]=u0.w;
            b[4]=u1.x; b[5]=u1.y; b[6]=u1.z; b[7]=u1.w;
#pragma unroll
            for (int i = 0; i < 8; ++i)
#pragma unroll
                for (int j = 0; j < 8; ++j)
                    acc[i][j] += a[i] * b[j];
        }
    }

    // epilogue: + bias, two float4 stores per row (verified bit-exact in R2)
#pragma unroll
    for (int i = 0; i < 8; ++i) {
        const int r = row0 + ty * 8 + i;
        const int c0 = col0 + tx * 4;
        const int c1 = col0 + 64 + tx * 4;
        float4 o0, o1;
        o0.x = acc[i][0] + bias[c0 + 0];
        o0.y = acc[i][1] + bias[c0 + 1];
        o0.z = acc[i][2] + bias[c0 + 2];
        o0.w = acc[i][3] + bias[c0 + 3];
        o1.x = acc[i][4] + bias[c1 + 0];
        o1.y = acc[i][5] + bias[c1 + 1];
        o1.z = acc[i][6] + bias[c1 + 2];
        o1.w = acc[i][7] + bias[c1 + 3];
        *reinterpret_cast<float4*>(&C[(size_t)r * NN + c0]) = o0;
        *reinterpret_cast<float4*>(&C[(size_t)r * NN + c1]) = o1;
    }
#undef LOADREG
#undef STOREV
}

// ---------------- Sequential LIF scan (in-place over cur/mem buffer) ----------------
__global__ __launch_bounds__(256) void snn_scan(float* buf, float* spk) {
    const int BH = BATCH * D_HH;  // 131072
    const int i = blockIdx.x * 256 + threadIdx.x;
    float mem = 0.0f;
    float c = buf[i];  // prefetch t=0
    for (int t = 0; t < T_STEPS; ++t) {
        float cn = (t + 1 < T_STEPS) ? buf[(size_t)(t + 1) * BH + i] : 0.0f;
        const float reset = (mem > 1.0f) ? 1.0f : 0.0f;
        mem = 0.9f * mem + c - reset;
        const float s = (mem > 1.0f) ? 1.0f : 0.0f;
        spk[(size_t)t * BH + i] = s;
        buf[(size_t)t * BH + i] = mem;
        c = cn;
    }
}

extern "C" void kernel_launch(void* const* d_in, const int* in_sizes, int n_in,
                              void* d_out, int out_size, void* d_ws, size_t ws_size,
                              hipStream_t stream) {
    const float* x    = (const float*)d_in[0];  // [T,B,D_IN]
    const float* W    = (const float*)d_in[1];  // [D_H,D_IN]
    const float* bias = (const float*)d_in[2];  // [D_H]
    float* out = (float*)d_out;

    const size_t TBH = (size_t)T_STEPS * BATCH * D_HH;
    float* spk = out;        // first half
    float* mem = out + TBH;  // second half; holds cur between the two kernels

    dim3 grid(MM / BM, NN / BN);  // 400 x 4
    gemm_nt_f32<<<grid, 256, 0, stream>>>(x, W, bias, mem);

    snn_scan<<<(BATCH * D_HH) / 256, 256, 0, stream>>>(mem, spk);
}